// Round 10
// baseline (63.978 us; speedup 1.0000x reference)
//
#include <hip/hip_runtime.h>
#include <hip/hip_bf16.h>

#define DIM 384
#define RED 16
#define PAIR 128
#define B 2
#define M 512
#define EPSV 1e-5f

typedef float f32x4 __attribute__((ext_vector_type(4)));
typedef short bf16x8 __attribute__((ext_vector_type(8)));

__device__ __forceinline__ unsigned short f2bf(float f) {
  union { float f; unsigned u; } v; v.f = f;
  unsigned r = v.u + 0x7fffu + ((v.u >> 16) & 1u);   // RTN-even
  return (unsigned short)(r >> 16);
}

// ---------------------------------------------------------------------------
// K1 (xr only): one wave per row. LN(384) in-register (xor butterfly),
// xn staged in wave-private LDS, xr[16] = xn @ w_red + b_red.
// Writes xr as bf16 (MFMA operand) and fp32 (for T compute in K2).
// grid = B*M/4 = 256 blocks x 256 thr (4 waves = 4 rows). No barriers.
// ---------------------------------------------------------------------------
__global__ __launch_bounds__(256) void opm_k1(
    const float* __restrict__ x, const float* __restrict__ g,
    const float* __restrict__ be, const float* __restrict__ w_red,
    const float* __restrict__ b_red,
    unsigned short* __restrict__ xr_bf, float* __restrict__ xr_f32) {
  const int wave = threadIdx.x >> 6;
  const int lane = threadIdx.x & 63;
  const int row  = blockIdx.x * 4 + wave;

  __shared__ float xn_s[4][DIM];

  const float* xrow = x + (size_t)row * DIM;
  float v[6];
  #pragma unroll
  for (int k = 0; k < 6; ++k) v[k] = xrow[lane + 64 * k];
  float s = 0.f, sq = 0.f;
  #pragma unroll
  for (int k = 0; k < 6; ++k) { s += v[k]; sq += v[k] * v[k]; }
  #pragma unroll
  for (int off = 32; off > 0; off >>= 1) {
    s  += __shfl_xor(s, off);
    sq += __shfl_xor(sq, off);
  }
  const float mean = s * (1.0f / DIM);
  const float var  = sq * (1.0f / DIM) - mean * mean;
  const float rstd = rsqrtf(var + EPSV);
  #pragma unroll
  for (int k = 0; k < 6; ++k) {
    const int d = lane + 64 * k;
    xn_s[wave][d] = (v[k] - mean) * rstd * g[d] + be[d];
  }
  // wave-private LDS: no barrier needed (same wave writes & reads)

  const int r = lane & 15, part = lane >> 4;
  const int d0 = part * 96;
  float ps = 0.f;
  #pragma unroll 4
  for (int d = d0; d < d0 + 96; ++d) ps += xn_s[wave][d] * w_red[d * RED + r];
  ps += __shfl_xor(ps, 16);
  ps += __shfl_xor(ps, 32);
  if (lane < 16) {
    const float val = ps + b_red[lane];
    xr_f32[(size_t)row * RED + lane] = val;
    xr_bf [(size_t)row * RED + lane] = f2bf(val);
  }
}

// ---------------------------------------------------------------------------
// K2 (fused T + MFMA, persistent over m):
//   T[n][i][p] = sum_j xr[n][j] * w_out[(i*16+j)*128+p]   (in-block, LDS)
//   out[b,m,n,p] = b_out[p] + sum_i T[n][i][p] * xr[m][i]  (MFMA, swapped ops)
// Each block owns a 4-n slice + m-half. Prologue: stage xr_f32 (4x16),
// compute T into 16 KB LDS (bf16, [n][p][i]), 2 barriers. Main loop =
// round-9 persistent MFMA loop (barrier-free, one dwordx4 store per MFMA).
// grid = B * 128 n-groups * 2 m-halves = 512 blocks x 256 thr.
// ---------------------------------------------------------------------------
__global__ __launch_bounds__(256) void opm_k2(
    const unsigned short* __restrict__ xr_bf, const float* __restrict__ xr_f32,
    const float* __restrict__ w_out, const float* __restrict__ b_out,
    float* __restrict__ out) {
  const int nb = blockIdx.x & 127;          // n-group (M/4 = 128)
  const int mh = (blockIdx.x >> 7) & 1;     // m-half
  const int b  = blockIdx.x >> 8;
  const int tid  = threadIdx.x;
  const int wave = tid >> 6;
  const int lane = tid & 63;
  const int q = lane >> 4;                  // k-quad
  const int r = lane & 15;                  // A-row (p) / D-col (m)
  const int n = nb * 4 + wave;

  __shared__ float xr_lds[4][RED];
  __shared__ unsigned short T_lds[4][PAIR][RED];   // 16 KB, [n_loc][p][i]

  if (tid < 64) {
    const int nl = tid >> 4, j = tid & 15;
    xr_lds[nl][j] = xr_f32[(size_t)(b * M + nb * 4 + nl) * RED + j];
  }
  __syncthreads();

  // ---- T compute: thread (h2=tid>>7, p=tid&127) -> rows 2h2, 2h2+1 ----
  {
    const int h2 = tid >> 7;
    const int p  = tid & 127;
    const float* W = w_out + p;
    const float* x0 = xr_lds[2 * h2];
    const float* x1 = xr_lds[2 * h2 + 1];
    unsigned int* dst0 = (unsigned int*)&T_lds[2 * h2][p][0];
    unsigned int* dst1 = (unsigned int*)&T_lds[2 * h2 + 1][p][0];
    #pragma unroll
    for (int i = 0; i < RED; i += 2) {
      float a00 = 0.f, a01 = 0.f, a10 = 0.f, a11 = 0.f;
      #pragma unroll
      for (int j = 0; j < RED; ++j) {
        const float w0 = W[(i * RED + j) * PAIR];
        const float w1 = W[((i + 1) * RED + j) * PAIR];
        a00 += x0[j] * w0;  a01 += x0[j] * w1;
        a10 += x1[j] * w0;  a11 += x1[j] * w1;
      }
      dst0[i >> 1] = (unsigned)f2bf(a00) | ((unsigned)f2bf(a01) << 16);
      dst1[i >> 1] = (unsigned)f2bf(a10) | ((unsigned)f2bf(a11) << 16);
    }
  }
  __syncthreads();

  // ---- A fragments (T): tv[pb] lane(q,r) = T[n][i=8q..8q+7][pb*16+r] ----
  bf16x8 tv[8];
  #pragma unroll
  for (int pb = 0; pb < 8; ++pb) {
    bf16x8 v = {0, 0, 0, 0, 0, 0, 0, 0};
    if (q < 2) v = *(const bf16x8*)&T_lds[wave][pb * 16 + r][q * 8];
    tv[pb] = v;
  }
  f32x4 biasv[8];
  #pragma unroll
  for (int pb = 0; pb < 8; ++pb)
    biasv[pb] = *(const f32x4*)(b_out + pb * 16 + q * 4);

  const unsigned short* xr_base = xr_bf + (size_t)(b * M) * RED;
  float* out_base = out + ((size_t)(b * M) * M + n) * PAIR + q * 4;

  #pragma unroll
  for (int mt4 = 0; mt4 < 4; ++mt4) {
    const int mt = mh * 4 + mt4;
    #pragma unroll
    for (int ms = 0; ms < 4; ++ms) {
      const int m0 = mt * 64 + ms * 16;
      // B fragment (xr): lane(q,r) holds xr[m0+r][8q..8q+7]; q>=2 -> 0
      bf16x8 xv = {0, 0, 0, 0, 0, 0, 0, 0};
      if (q < 2) xv = *(const bf16x8*)(xr_base + (size_t)(m0 + r) * RED + q * 8);

      float* ob = out_base + (size_t)(m0 + r) * M * PAIR;
      #pragma unroll
      for (int pb = 0; pb < 8; ++pb) {
        f32x4 acc = biasv[pb];
        acc = __builtin_amdgcn_mfma_f32_16x16x32_bf16(tv[pb], xv, acc, 0, 0, 0);
        *(f32x4*)(ob + pb * 16) = acc;
      }
    }
  }
}

extern "C" void kernel_launch(void* const* d_in, const int* in_sizes, int n_in,
                              void* d_out, int out_size, void* d_ws, size_t ws_size,
                              hipStream_t stream) {
  const float* x       = (const float*)d_in[0];
  const float* ln_g    = (const float*)d_in[1];
  const float* ln_b    = (const float*)d_in[2];
  const float* w_red   = (const float*)d_in[3];
  const float* b_red   = (const float*)d_in[4];
  const float* w_out   = (const float*)d_in[5];
  const float* b_out   = (const float*)d_in[6];
  float* out = (float*)d_out;

  unsigned short* xr_bf  = (unsigned short*)d_ws;                 // 32 KB
  float*          xr_f32 = (float*)(xr_bf + (size_t)B * M * RED); // 64 KB

  opm_k1<<<B * M / 4, 256, 0, stream>>>(x, ln_g, ln_b, w_red, b_red, xr_bf, xr_f32);
  opm_k2<<<B * (M / 4) * 2, 256, 0, stream>>>(xr_bf, xr_f32, w_out, b_out, out);
}